// Round 13
// baseline (79.436 us; speedup 1.0000x reference)
//
#include <hip/hip_runtime.h>

#pragma clang fp contract(off)

#define NB 8
#define NN 25200
#define NCLS 80
#define NSTR 85
#define MAXDET 300
#define CONF_T 0.4f
#define IOU_T 0.45f
#define MAX_WH_C 4096.0f

#define NBIN 1024
#define BINSHIFT 14
#define BINBASE 0x3EC00000u   // bits(0.375) < bits of any valid score (>0.4)
#define SELN 512
#define SORTN 2048            // tiny-ws fallback kernel only
#define PREP_ROWS 64

typedef unsigned long long ull;

// ---------------- helpers ----------------
__device__ __forceinline__ float cand_score(const float* __restrict__ p) {
    float obj = p[4];
    float best = p[5] * obj;
    for (int j = 1; j < NCLS; ++j) {
        float s = p[5 + j] * obj;
        if (s > best) best = s;
    }
    return ((obj > CONF_T) && (best > CONF_T)) ? best : -1.0f;
}
__device__ __forceinline__ int cand_cls(const float* __restrict__ p) {
    float obj = p[4];
    float best = p[5] * obj; int bc = 0;
    for (int j = 1; j < NCLS; ++j) {
        float s = p[5 + j] * obj;
        if (s > best) { best = s; bc = j; }   // strict >: first-index argmax
    }
    return bc;
}
__device__ __forceinline__ bool iou_gt(float ax1, float ay1, float ax2, float ay2, float aarea,
                                       float bx1, float by1, float bx2, float by2, float barea) {
    float lx = fmaxf(ax1, bx1);
    float ly = fmaxf(ay1, by1);
    float rx = fminf(ax2, bx2);
    float ry = fminf(ay2, by2);
    float iw = fmaxf(rx - lx, 0.0f);
    float ih = fmaxf(ry - ly, 0.0f);
    float inter = iw * ih;
    float iou = inter / ((aarea + barea - inter) + 1e-9f);
    return iou > IOU_T;
}

// =============== Kernel 1: score + class (float4 LDS staging) ===============
__global__ __launch_bounds__(256) void prep_kernel(const float* __restrict__ pred,
                                                   float* __restrict__ score_ws,
                                                   int* __restrict__ cls_ws,
                                                   int write_cls) {
    __shared__ float st[PREP_ROWS * NSTR];   // 21760 B
    const int R0 = blockIdx.x * PREP_ROWS;
    const float4* src = reinterpret_cast<const float4*>(pred + (size_t)R0 * NSTR);
    float4* dst4 = reinterpret_cast<float4*>(st);
    const int tid = threadIdx.x;
    for (int i = tid; i < PREP_ROWS * NSTR / 4; i += 256) dst4[i] = src[i];
    __syncthreads();

    int row = tid >> 2, part = tid & 3;
    const float* pr = st + row * NSTR;
    float obj = pr[4];
    float best = -1.0f; int bc = part * 20;
    const float* pc = pr + 5 + part * 20;
#pragma unroll
    for (int k = 0; k < 20; ++k) {
        float s = pc[k] * obj;
        if (s > best) { best = s; bc = part * 20 + k; }
    }
#pragma unroll
    for (int d = 1; d <= 2; d <<= 1) {
        float ob = __shfl_xor(best, d);
        int   oc = __shfl_xor(bc, d);
        if (ob > best || (ob == best && oc < bc)) { best = ob; bc = oc; }
    }
    if (part == 0) {
        int grow = R0 + row;
        bool valid = (obj > CONF_T) && (best > CONF_T);
        score_ws[grow] = valid ? best : -1.0f;
        if (write_cls) cls_ws[grow] = bc;
    }
}

// =============== Kernel 2 (full-ws): fused select+attrs+mask, 4 blocks/image, 1024 thr ===============
__global__ __launch_bounds__(1024) void selmask3_kernel(const float* __restrict__ pred,
        const float* __restrict__ score_ws, const int* __restrict__ cls_ws,
        int* __restrict__ cnt_ws, int* __restrict__ total_ws,
        ull* __restrict__ sel_key,
        float* __restrict__ sel_x1, float* __restrict__ sel_y1,
        float* __restrict__ sel_x2, float* __restrict__ sel_y2,
        float* __restrict__ sel_area, float* __restrict__ sel_cls,
        int* __restrict__ sel_idx,
        ull* __restrict__ mask_ws) {
    __shared__ int s_hist[NBIN];                 // 4 KB
    __shared__ int s_c[1024], s_off[1024];       // 8 KB
    __shared__ ull s_key[SELN];                  // 4 KB
    __shared__ int s_gidx[SELN];                 // 2 KB
    __shared__ float m_x1[SELN], m_y1[SELN], m_x2[SELN], m_y2[SELN], m_ar[SELN], m_cl[SELN]; // 12 KB
    __shared__ int sT, sTot, sSel;

    const int b = blockIdx.x >> 2;
    const int quarter = blockIdx.x & 3;
    const int tid = threadIdx.x;
    const int lane = tid & 63;
    const float* sb = score_ws + (size_t)b * NN;
    const float* predb = pred + (size_t)b * NN * NSTR;

    // ---- hist (identical in all 4 blocks of the image) ----
    s_hist[tid] = 0;
    __syncthreads();
    for (int g = tid; g < NN; g += 1024) {
        float s = sb[g];
        if (s > 0.0f) {
            int bin = (int)((__float_as_uint(s) - BINBASE) >> BINSHIFT);
            atomicAdd(&s_hist[bin], 1);
        }
    }
    __syncthreads();

    // ---- threshold (wave 0, suffix scan over 1024 bins) ----
    if (tid < 64) {
        int acc = 0; int S[16];
#pragma unroll
        for (int k = 15; k >= 0; --k) { acc += s_hist[lane * 16 + k]; S[k] = acc; }
        int tot = acc;
        int incl = tot;
#pragma unroll
        for (int d = 1; d < 64; d <<= 1) {
            int v = __shfl_down(incl, d);
            if (lane + d < 64) incl += v;
        }
        int E = incl - tot;   // sum over lanes > lane
        int Tl = NBIN;
#pragma unroll
        for (int k = 0; k < 16; ++k)
            if (Tl == NBIN && S[k] + E <= SELN) Tl = lane * 16 + k;
        int total0 = incl;    // lane 0: grand total
#pragma unroll
        for (int d = 1; d < 64; d <<= 1) {
            int o = __shfl_xor(Tl, d);
            if (o < Tl) Tl = o;
        }
        if (lane == 0) { sT = Tl; sTot = total0; }
    }
    __syncthreads();
    int T = sT;

    // ---- deterministic compaction (count / scan / place), coalesced stride-1024 ----
    int c = 0;
    for (int g = tid; g < NN; g += 1024) {
        float s = sb[g];
        if (s > 0.0f && (int)((__float_as_uint(s) - BINBASE) >> BINSHIFT) >= T) ++c;
    }
    s_c[tid] = c;
    __syncthreads();
    if (tid < 64) {
        int base = tid << 4;   // 16 counts per lane
        int pre[16]; int run = 0;
#pragma unroll
        for (int k = 0; k < 16; ++k) { pre[k] = run; run += s_c[base + k]; }
        int inc = run;
#pragma unroll
        for (int d = 1; d < 64; d <<= 1) {
            int v = __shfl_up(inc, d);
            if (lane >= d) inc += v;
        }
        int ex = inc - run;
#pragma unroll
        for (int k = 0; k < 16; ++k) s_off[base + k] = ex + pre[k];
        if (lane == 63) sSel = ex + run;
    }
    __syncthreads();
    {
        int r = s_off[tid];
        for (int g = tid; g < NN; g += 1024) {
            float s = sb[g];
            if (s > 0.0f && (int)((__float_as_uint(s) - BINBASE) >> BINSHIFT) >= T) {
                if (r < SELN) {
                    s_key[r] = ((ull)__float_as_uint(s) << 32)
                               | (unsigned int)(0xFFFFFFFFu - (unsigned int)g);
                    s_gidx[r] = g;
                }
                ++r;
            }
        }
    }
    __syncthreads();
    int cnt = sSel; if (cnt > SELN) cnt = SELN;

    // ---- attrs: 1 slot/thread, 4-float pred read + precomputed cls ----
    if (tid < cnt) {
        int g = s_gidx[tid];
        const float* p = predb + (size_t)g * NSTR;
        float cx = p[0], cy = p[1], w = p[2], h = p[3];
        int cc = cls_ws[(size_t)b * NN + g];
        float off = (float)cc * MAX_WH_C;
        float x1 = (cx - w * 0.5f) + off;
        float y1 = (cy - h * 0.5f) + off;
        float x2 = (cx + w * 0.5f) + off;
        float y2 = (cy + h * 0.5f) + off;
        m_x1[tid] = x1; m_y1[tid] = y1; m_x2[tid] = x2; m_y2[tid] = y2;
        m_ar[tid] = (x2 - x1) * (y2 - y1);
        m_cl[tid] = (float)cc;
    }
    __syncthreads();

    // ---- this block's 128 mask rows (w=tid>>7 so j-reads are wave-broadcast) ----
    {
        int w = tid >> 7;                   // 0..7
        int i = quarter * 128 + (tid & 127);
        if (i < cnt) {
            ull ki = s_key[i];
            float ax1 = m_x1[i], ay1 = m_y1[i], ax2 = m_x2[i], ay2 = m_y2[i], aar = m_ar[i];
            ull m = 0ull;
            int jb = w << 6;
            int jend = cnt - jb; if (jend > 64) jend = 64;
            for (int t = 0; t < jend; ++t) {
                int j = jb + t;
                // j suppresses i iff j precedes i in score order AND IoU > thresh
                bool sres = (s_key[j] > ki) && iou_gt(ax1, ay1, ax2, ay2, aar,
                                                     m_x1[j], m_y1[j], m_x2[j], m_y2[j], m_ar[j]);
                m |= (ull)sres << t;
            }
            mask_ws[b * (8 * SELN) + w * SELN + i] = m;
        }
    }

    // ---- quarter 0 publishes selection (identical across blocks, deterministic) ----
    if (quarter == 0) {
        for (int s = tid; s < cnt; s += 1024) {
            int o = b * SELN + s;
            sel_key[o] = s_key[s];
            sel_x1[o] = m_x1[s]; sel_y1[o] = m_y1[s];
            sel_x2[o] = m_x2[s]; sel_y2[o] = m_y2[s];
            sel_area[o] = m_ar[s]; sel_cls[o] = m_cl[s];
            sel_idx[o] = s_gidx[s];
        }
        if (tid == 0) { cnt_ws[b] = cnt; total_ws[b] = sTot; }
    }
}

// =============== Kernel 2m (mid-ws): per-image hist+threshold+compact+attrs (8 blocks) ===============
__global__ __launch_bounds__(1024) void selimg_kernel(const float* __restrict__ pred,
                                                      const float* __restrict__ score_ws,
                                                      int* __restrict__ cnt_ws, int* __restrict__ total_ws,
                                                      ull* __restrict__ sel_key,
                                                      float* __restrict__ sel_x1, float* __restrict__ sel_y1,
                                                      float* __restrict__ sel_x2, float* __restrict__ sel_y2,
                                                      float* __restrict__ sel_area, float* __restrict__ sel_cls,
                                                      int* __restrict__ sel_idx) {
    __shared__ int s_hist[NBIN];
    __shared__ ull s_key[SELN];
    __shared__ int s_gidx[SELN];
    __shared__ int s_cnt, s_T, s_total;
    const int b = blockIdx.x;
    const int tid = threadIdx.x;
    const int lane = tid & 63;
    const int wid = tid >> 6;
    const float* predb = pred + (size_t)b * NN * NSTR;
    const float* sb = score_ws + (size_t)b * NN;

    s_hist[tid] = 0;
    if (tid == 0) s_cnt = 0;
    __syncthreads();
    for (int g = tid; g < NN; g += 1024) {
        float s = sb[g];
        if (s > 0.0f) {
            int bin = (int)((__float_as_uint(s) - BINBASE) >> BINSHIFT);
            atomicAdd(&s_hist[bin], 1);
        }
    }
    __syncthreads();
    if (wid == 0) {
        int acc = 0; int S[16];
#pragma unroll
        for (int k = 15; k >= 0; --k) { acc += s_hist[lane * 16 + k]; S[k] = acc; }
        int tot = acc;
        int incl = tot;
#pragma unroll
        for (int d = 1; d < 64; d <<= 1) {
            int v = __shfl_down(incl, d);
            if (lane + d < 64) incl += v;
        }
        int E = incl - tot;
        int Tl = NBIN;
#pragma unroll
        for (int k = 0; k < 16; ++k)
            if (Tl == NBIN && S[k] + E <= SELN) Tl = lane * 16 + k;
        int total0 = incl;
#pragma unroll
        for (int d = 1; d < 64; d <<= 1) {
            int o = __shfl_xor(Tl, d);
            if (o < Tl) Tl = o;
        }
        if (lane == 0) { s_T = Tl; s_total = total0; }
    }
    __syncthreads();
    int T = s_T;
    for (int g = tid; g < NN; g += 1024) {
        float s = sb[g];
        if (s > 0.0f) {
            int bin = (int)((__float_as_uint(s) - BINBASE) >> BINSHIFT);
            if (bin >= T) {
                int pos = atomicAdd(&s_cnt, 1);
                if (pos < SELN) {
                    s_key[pos] = ((ull)__float_as_uint(s) << 32)
                                 | (unsigned int)(0xFFFFFFFFu - (unsigned int)g);
                    s_gidx[pos] = g;
                }
            }
        }
    }
    __syncthreads();
    int cnt = s_cnt; if (cnt > SELN) cnt = SELN;

    if (tid < cnt) {
        int g = s_gidx[tid];
        const float* p = predb + (size_t)g * NSTR;
        float cx = p[0], cy = p[1], w = p[2], h = p[3];
        int c = cand_cls(p);
        float off = (float)c * MAX_WH_C;
        float x1 = (cx - w * 0.5f) + off;
        float y1 = (cy - h * 0.5f) + off;
        float x2 = (cx + w * 0.5f) + off;
        float y2 = (cy + h * 0.5f) + off;
        int o = b * SELN + tid;
        sel_key[o] = s_key[tid];
        sel_x1[o] = x1; sel_y1[o] = y1; sel_x2[o] = x2; sel_y2[o] = y2;
        sel_area[o] = (x2 - x1) * (y2 - y1);
        sel_cls[o] = (float)c;
        sel_idx[o] = g;
    }
    if (tid == 0) { cnt_ws[b] = cnt; total_ws[b] = s_total; }
}

// =============== Kernel 3m (mid-ws): mask in slot space (128 blocks) ===============
__global__ __launch_bounds__(256) void mask_kernel(const int* __restrict__ cnt_ws,
                                                   const ull* __restrict__ sel_key,
                                                   const float* __restrict__ sel_x1, const float* __restrict__ sel_y1,
                                                   const float* __restrict__ sel_x2, const float* __restrict__ sel_y2,
                                                   const float* __restrict__ sel_area,
                                                   ull* __restrict__ mask_ws) {
    __shared__ ull skey[SELN];
    __shared__ float ox1[SELN], oy1[SELN], ox2[SELN], oy2[SELN], oar[SELN];
    const int b = blockIdx.x >> 4;
    const int chunk = blockIdx.x & 15;
    const int tid = threadIdx.x;
    int cnt = cnt_ws[b]; if (cnt > SELN) cnt = SELN;
    for (int s = tid; s < SELN; s += 256) {
        if (s < cnt) {
            skey[s] = sel_key[b * SELN + s];
            ox1[s] = sel_x1[b * SELN + s]; oy1[s] = sel_y1[b * SELN + s];
            ox2[s] = sel_x2[b * SELN + s]; oy2[s] = sel_y2[b * SELN + s];
            oar[s] = sel_area[b * SELN + s];
        } else skey[s] = 0ull;
    }
    __syncthreads();
    int i = chunk * 32 + (tid & 31);
    int w = tid >> 5;
    if (i < cnt) {
        ull ki = skey[i];
        float ax1 = ox1[i], ay1 = oy1[i], ax2 = ox2[i], ay2 = oy2[i], aar = oar[i];
        ull m = 0ull;
        int jb = w << 6;
        int jend = cnt - jb; if (jend > 64) jend = 64;
        for (int t = 0; t < jend; ++t) {
            int j = jb + t;
            bool s = (skey[j] > ki) && iou_gt(ax1, ay1, ax2, ay2, aar,
                                             ox1[j], oy1[j], ox2[j], oy2[j], oar[j]);
            m |= (ull)s << t;
        }
        mask_ws[b * (8 * SELN) + w * SELN + i] = m;
    }
}

// =============== Kernel 4: Jacobi fixpoint (slot space) + ordered output ===============
__global__ __launch_bounds__(1024) void resolve_kernel(
        const float* __restrict__ pred, const float* __restrict__ logits,
        const float* __restrict__ score_ws, const int* __restrict__ cls_ws, int use_cls,
        const int* __restrict__ cnt_ws, const int* __restrict__ total_ws,
        const ull* __restrict__ mask_ws, const ull* __restrict__ sel_key,
        const float* __restrict__ sel_x1, const float* __restrict__ sel_y1,
        const float* __restrict__ sel_x2, const float* __restrict__ sel_y2,
        const float* __restrict__ sel_area, const float* __restrict__ sel_cls,
        const int* __restrict__ sel_idx,
        float* __restrict__ out) {
    __shared__ ull s_m[8][SELN];
    __shared__ ull s_key[SELN];
    __shared__ ull s_kw[8];
    __shared__ ull s_minkey;
    __shared__ float s_x1[SELN], s_y1[SELN], s_x2[SELN], s_y2[SELN], s_ar[SELN], s_cl[SELN];
    __shared__ int s_ix[SELN];
    __shared__ float kx1[MAXDET], ky1[MAXDET], kx2[MAXDET], ky2[MAXDET], kar[MAXDET];
    __shared__ float ksc[MAXDET], kcl[MAXDET];
    __shared__ int kix[MAXDET];
    __shared__ int s_kc;

    const int b = blockIdx.x;
    const int tid = threadIdx.x;
    const int lane = tid & 63;
    const int wid = tid >> 6;
    const float* predb = pred + (size_t)b * NN * NSTR;
    const float* logb  = logits + (size_t)b * NN * NCLS;
    const float* sb    = score_ws + (size_t)b * NN;

    int cnt = cnt_ws[b]; if (cnt > SELN) cnt = SELN;

    for (int i = tid; i < 8 * SELN; i += 1024)
        (&s_m[0][0])[i] = mask_ws[b * (8 * SELN) + i];
    for (int s = tid; s < SELN; s += 1024) {
        if (s < cnt) {
            s_key[s] = sel_key[b * SELN + s];
            s_x1[s] = sel_x1[b * SELN + s]; s_y1[s] = sel_y1[b * SELN + s];
            s_x2[s] = sel_x2[b * SELN + s]; s_y2[s] = sel_y2[b * SELN + s];
            s_ar[s] = sel_area[b * SELN + s]; s_cl[s] = sel_cls[b * SELN + s];
            s_ix[s] = sel_idx[b * SELN + s];
        } else s_key[s] = 0ull;
    }
    __syncthreads();

    if (wid == 0) {
        ull mk = ~0ull;
#pragma unroll
        for (int r = 0; r < 8; ++r) {
            int i = (r << 6) + lane;
            if (i < cnt) { ull k = s_key[i]; if (k < mk) mk = k; }
        }
#pragma unroll
        for (int d = 32; d >= 1; d >>= 1) {
            ull o = __shfl_xor(mk, d);
            if (o < mk) mk = o;
        }
        if (lane == 0) s_minkey = mk;

        ull vm[8], kw[8];
#pragma unroll
        for (int r = 0; r < 8; ++r) {
            int lo = r << 6;
            vm[r] = (cnt >= lo + 64) ? ~0ull : (cnt > lo ? ((1ull << (cnt - lo)) - 1ull) : 0ull);
            kw[r] = vm[r];
        }
        for (int round = 0; round < SELN; ++round) {
            ull nw[8];
#pragma unroll
            for (int r = 0; r < 8; ++r) {
                int i = (r << 6) + lane;
                ull supp = 0ull;
#pragma unroll
                for (int w = 0; w < 8; ++w) supp |= kw[w] & s_m[w][i];
                nw[r] = __ballot((int)(supp == 0ull)) & vm[r];
            }
            bool changed = false;
#pragma unroll
            for (int r = 0; r < 8; ++r) { changed |= (nw[r] != kw[r]); kw[r] = nw[r]; }
            if (!changed) break;
        }
        int totkept = 0;
#pragma unroll
        for (int r = 0; r < 8; ++r) totkept += __popcll(kw[r]);
        if (lane == 0) s_kc = totkept < MAXDET ? totkept : MAXDET;
        if (lane < 8) s_kw[lane] = kw[lane];
    }
    __syncthreads();
    int kc = s_kc;

    if (tid < SELN) {
        bool kept = (s_kw[tid >> 6] >> (tid & 63)) & 1ull;
        if (!kept) s_key[tid] = 0ull;
    }
    __syncthreads();

    {
        int i = tid >> 1, half = tid & 1;
        ull k = s_key[i];
        int r = 0;
        if (k != 0ull) {
            int jb = half << 8;
            for (int jj = 0; jj < 256; ++jj) {
                ull kj = s_key[jb + jj];
                r += (int)(kj > k);
            }
        }
        r += __shfl_xor(r, 1);
        if (half == 0 && k != 0ull && r < MAXDET) {
            kx1[r] = s_x1[i]; ky1[r] = s_y1[i]; kx2[r] = s_x2[i]; ky2[r] = s_y2[i];
            kar[r] = s_ar[i]; ksc[r] = __uint_as_float((unsigned int)(k >> 32));
            kcl[r] = s_cl[i]; kix[r] = s_ix[i];
        }
    }
    __syncthreads();

    if (wid == 0 && kc < MAXDET && total_ws[b] > cnt) {
        ull prevkey = (cnt > 0) ? s_minkey : ~0ull;
        while (kc < MAXDET) {
            ull best = 0ull;
            for (int i0 = lane; i0 < NN; i0 += 64) {
                float s = sb[i0];
                if (s > 0.0f) {
                    ull key = ((ull)__float_as_uint(s) << 32)
                              | (unsigned int)(0xFFFFFFFFu - (unsigned int)i0);
                    if (key < prevkey && key > best) best = key;
                }
            }
#pragma unroll
            for (int d = 32; d >= 1; d >>= 1) {
                ull o = __shfl_xor(best, d);
                if (o > best) best = o;
            }
            if (best == 0ull) break;
            prevkey = best;
            int gi = (int)(0xFFFFFFFFu - (unsigned int)(best & 0xFFFFFFFFull));
            float sc = __uint_as_float((unsigned int)(best >> 32));
            const float* pp = predb + (size_t)gi * NSTR;
            float cx = pp[0], cy = pp[1], w = pp[2], h = pp[3];
            int c = use_cls ? cls_ws[(size_t)b * NN + gi] : cand_cls(pp);
            float off = (float)c * MAX_WH_C;
            float x1 = (cx - w * 0.5f) + off;
            float y1 = (cy - h * 0.5f) + off;
            float x2 = (cx + w * 0.5f) + off;
            float y2 = (cy + h * 0.5f) + off;
            float ar = (x2 - x1) * (y2 - y1);
            bool f = false;
            for (int t = lane; t < kc; t += 64)
                if (iou_gt(kx1[t], ky1[t], kx2[t], ky2[t], kar[t], x1, y1, x2, y2, ar)) f = true;
            if (!__any((int)f)) {
                if (lane == 0) {
                    kx1[kc] = x1; ky1[kc] = y1; kx2[kc] = x2; ky2[kc] = y2;
                    kar[kc] = ar; ksc[kc] = sc; kcl[kc] = (float)c; kix[kc] = gi;
                }
                kc++;
            }
        }
        if (lane == 0) s_kc = kc;
    }
    __syncthreads();
    kc = s_kc;

    if (tid < MAXDET) {
        int t = tid;
        float o0 = 0, o1 = 0, o2 = 0, o3 = 0, o4 = 0, o5 = 0;
        if (t < kc) {
            int idx = kix[t];
            const float* pp = predb + (size_t)idx * NSTR;
            float cx = pp[0], cy = pp[1], w = pp[2], h = pp[3];
            o0 = cx - w * 0.5f; o1 = cy - h * 0.5f;
            o2 = cx + w * 0.5f; o3 = cy + h * 0.5f;
            o4 = ksc[t];        o5 = kcl[t];
        }
        float* dd = out + (size_t)b * (MAXDET * 6) + (size_t)t * 6;
        dd[0] = o0; dd[1] = o1; dd[2] = o2; dd[3] = o3; dd[4] = o4; dd[5] = o5;
        out[(size_t)NB * MAXDET * 6 + (size_t)NB * MAXDET * NCLS + (size_t)b * MAXDET + t] =
            (t < kc) ? 1.0f : 0.0f;
    }
    float* lbase = out + (size_t)NB * MAXDET * 6 + (size_t)b * (MAXDET * NCLS);
    for (int t = wid; t < MAXDET; t += 16) {
        float* dst = lbase + (size_t)t * NCLS;
        if (t < kc) {
            const float* src = logb + (size_t)kix[t] * NCLS;
            for (int c = lane; c < NCLS; c += 64) dst[c] = src[c];
        } else {
            for (int c = lane; c < NCLS; c += 64) dst[c] = 0.0f;
        }
    }
}

// ================= tiny-ws fallback (self-contained, round-2 proven) =================
__global__ __launch_bounds__(1024) void fallback_kernel(const float* __restrict__ pred,
                                                        const float* __restrict__ logits,
                                                        float* __restrict__ out) {
    __shared__ ull s_keys[SORTN];
    __shared__ float sel_x1[SORTN], sel_y1[SORTN], sel_x2[SORTN], sel_y2[SORTN];
    __shared__ float sel_area[SORTN], sel_cls[SORTN];
    __shared__ int   sel_idx[SORTN];
    __shared__ float kx1[MAXDET], ky1[MAXDET], kx2[MAXDET], ky2[MAXDET], karea[MAXDET];
    __shared__ float kscore[MAXDET], kcls[MAXDET];
    __shared__ int   kidx[MAXDET];
    __shared__ int   s_hist[NBIN];
    __shared__ int   s_suppk[64];
    __shared__ unsigned int s_supmask[64][2];
    __shared__ int   s_kc, s_T, s_cnt;

    const int b = blockIdx.x;
    const int tid = threadIdx.x;
    const int lane = tid & 63;
    const int wid = tid >> 6;
    const float* predb = pred + (size_t)b * NN * NSTR;
    const float* logb  = logits + (size_t)b * NN * NCLS;

    int kc_total = 0;
    int prevT = NBIN;

    while (kc_total < MAXDET && prevT > 0) {
        s_hist[tid] = 0;
        if (tid == 0) { s_cnt = 0; s_T = NBIN; }
        __syncthreads();
        for (int i = tid; i < NN; i += 1024) {
            float s = cand_score(predb + (size_t)i * NSTR);
            if (s > 0.0f) {
                int bin = (int)((__float_as_uint(s) - BINBASE) >> BINSHIFT);
                if (bin < prevT) atomicAdd(&s_hist[bin], 1);
            }
        }
        __syncthreads();
        for (int d = 1; d < NBIN; d <<= 1) {
            int v = s_hist[tid] + ((tid + d < NBIN) ? s_hist[tid + d] : 0);
            __syncthreads();
            s_hist[tid] = v;
            __syncthreads();
        }
        if (s_hist[tid] <= SORTN) atomicMin(&s_T, tid);
        __syncthreads();
        int T = s_T;
        int rem_total = s_hist[0];
        if (T >= prevT) {
            if (rem_total == 0) { prevT = 0; break; }
            T = prevT - 1;
        }
        __syncthreads();
        for (int i = tid; i < NN; i += 1024) {
            float s = cand_score(predb + (size_t)i * NSTR);
            if (s > 0.0f) {
                int bin = (int)((__float_as_uint(s) - BINBASE) >> BINSHIFT);
                if (bin >= T && bin < prevT) {
                    int pos = atomicAdd(&s_cnt, 1);
                    if (pos < SORTN)
                        s_keys[pos] = ((ull)__float_as_uint(s) << 32)
                                      | (unsigned int)(0xFFFFFFFFu - (unsigned int)i);
                }
            }
        }
        __syncthreads();
        int cnt = s_cnt; if (cnt > SORTN) cnt = SORTN;
        int npow = 64; while (npow < cnt) npow <<= 1;
        for (int i = cnt + tid; i < npow; i += 1024) s_keys[i] = 0ull;
        __syncthreads();
        for (int k = 2; k <= npow; k <<= 1) {
            for (int j = k >> 1; j > 0; j >>= 1) {
                for (int idx = tid; idx < npow; idx += 1024) {
                    int p = idx ^ j;
                    if (p > idx) {
                        ull a = s_keys[idx], c = s_keys[p];
                        bool desc = ((idx & k) == 0);
                        if (desc ? (a < c) : (a > c)) { s_keys[idx] = c; s_keys[p] = a; }
                    }
                }
                __syncthreads();
            }
        }
        for (int t = tid; t < cnt; t += 1024) {
            ull key = s_keys[t];
            int i = (int)(0xFFFFFFFFu - (unsigned int)(key & 0xFFFFFFFFull));
            const float* p = predb + (size_t)i * NSTR;
            float cx = p[0], cy = p[1], w = p[2], h = p[3];
            int c = cand_cls(p);
            float off = (float)c * MAX_WH_C;
            float x1 = (cx - w * 0.5f) + off;
            float y1 = (cy - h * 0.5f) + off;
            float x2 = (cx + w * 0.5f) + off;
            float y2 = (cy + h * 0.5f) + off;
            sel_x1[t] = x1; sel_y1[t] = y1; sel_x2[t] = x2; sel_y2[t] = y2;
            sel_area[t] = (x2 - x1) * (y2 - y1);
            sel_cls[t] = (float)c;
            sel_idx[t] = i;
        }
        __syncthreads();
        int nb2 = (cnt + 63) >> 6;
        for (int batch = 0; batch < nb2; ++batch) {
            int kcb = kc_total;
            if (kcb >= MAXDET) break;
            if (tid < 64) { s_suppk[tid] = 0; s_supmask[tid][0] = 0u; s_supmask[tid][1] = 0u; }
            __syncthreads();
            int cloc = tid >> 4, ch = tid & 15;
            int gi = batch * 64 + cloc;
            bool validc = gi < cnt;
            float ax1 = 0, ay1 = 0, ax2 = 0, ay2 = 0, aar = 0;
            if (validc) {
                ax1 = sel_x1[gi]; ay1 = sel_y1[gi];
                ax2 = sel_x2[gi]; ay2 = sel_y2[gi]; aar = sel_area[gi];
            }
            bool flag = false;
            if (validc) {
                for (int t = ch; t < kcb; t += 16) {
                    if (iou_gt(kx1[t], ky1[t], kx2[t], ky2[t], karea[t],
                               ax1, ay1, ax2, ay2, aar)) flag = true;
                }
            }
            ull bal = __ballot((int)flag);
            if ((lane & 15) == 0) {
                unsigned int sub = (unsigned int)((bal >> (lane & 48)) & 0xFFFFull);
                s_suppk[cloc] = (sub != 0u);
            }
            unsigned int mbits = 0;
            if (validc) {
                for (int jj = 0; jj < 4; ++jj) {
                    int j = (ch << 2) + jj;
                    int gj = batch * 64 + j;
                    if (j > cloc && gj < cnt) {
                        if (iou_gt(ax1, ay1, ax2, ay2, aar,
                                   sel_x1[gj], sel_y1[gj], sel_x2[gj], sel_y2[gj], sel_area[gj]))
                            mbits |= 1u << (j & 31);
                    }
                }
            }
            if (mbits) atomicOr(&s_supmask[cloc][(ch >> 3) & 1], mbits);
            __syncthreads();
            if (wid == 0) {
                ull mask = ((ull)s_supmask[lane][1] << 32) | s_supmask[lane][0];
                bool validj = (batch * 64 + lane) < cnt;
                ull rem = __ballot((int)(validj && (s_suppk[lane] == 0)));
                ull keepbits = 0;
                int kcount = kcb;
                while (rem && kcount < MAXDET) {
                    int i = __builtin_ctzll(rem);
                    rem &= rem - 1;
                    keepbits |= 1ull << i;
                    ++kcount;
                    ull mi = __shfl(mask, i);
                    rem &= ~mi;
                }
                if ((keepbits >> lane) & 1ull) {
                    int pos = kcb + __popcll(keepbits & ((1ull << lane) - 1ull));
                    int g2 = batch * 64 + lane;
                    kx1[pos] = sel_x1[g2]; ky1[pos] = sel_y1[g2];
                    kx2[pos] = sel_x2[g2]; ky2[pos] = sel_y2[g2];
                    karea[pos] = sel_area[g2];
                    kcls[pos] = sel_cls[g2]; kidx[pos] = sel_idx[g2];
                    kscore[pos] = __uint_as_float((unsigned int)(s_keys[g2] >> 32));
                }
                if (lane == 0) s_kc = kcount;
            }
            __syncthreads();
            kc_total = s_kc;
            __syncthreads();
        }
        prevT = T;
    }

    __syncthreads();
    int kc = kc_total;
    if (tid < MAXDET) {
        int t = tid;
        float o0 = 0, o1 = 0, o2 = 0, o3 = 0, o4 = 0, o5 = 0;
        if (t < kc) {
            int idx = kidx[t];
            const float* pp = predb + (size_t)idx * NSTR;
            float cx = pp[0], cy = pp[1], w = pp[2], h = pp[3];
            o0 = cx - w * 0.5f; o1 = cy - h * 0.5f;
            o2 = cx + w * 0.5f; o3 = cy + h * 0.5f;
            o4 = kscore[t];     o5 = kcls[t];
        }
        float* dd = out + (size_t)b * (MAXDET * 6) + (size_t)t * 6;
        dd[0] = o0; dd[1] = o1; dd[2] = o2; dd[3] = o3; dd[4] = o4; dd[5] = o5;
        out[(size_t)NB * MAXDET * 6 + (size_t)NB * MAXDET * NCLS + (size_t)b * MAXDET + t] =
            (t < kc) ? 1.0f : 0.0f;
    }
    float* lbase = out + (size_t)NB * MAXDET * 6 + (size_t)b * (MAXDET * NCLS);
    for (int t = wid; t < MAXDET; t += 16) {
        float* dst = lbase + (size_t)t * NCLS;
        if (t < kc) {
            const float* src = logb + (size_t)kidx[t] * NCLS;
            for (int c = lane; c < NCLS; c += 64) dst[c] = src[c];
        } else {
            for (int c = lane; c < NCLS; c += 64) dst[c] = 0.0f;
        }
    }
}

extern "C" void kernel_launch(void* const* d_in, const int* in_sizes, int n_in,
                              void* d_out, int out_size, void* d_ws, size_t ws_size,
                              hipStream_t stream) {
    const float* pred   = (const float*)d_in[0];
    const float* logits = (const float*)d_in[1];
    float* out = (float*)d_out;

    // ws layout (8B arrays first)
    const size_t off_mask  = 0;                              // 8*4096*8 = 262144
    const size_t off_key   = 262144;                         // 8*512*8 = 32768
    const size_t off_flt   = 294912;                         // 6 * 16384 = 98304
    const size_t off_ix    = off_flt + 6 * 16384;            // 16384
    const size_t off_score = off_ix + 16384;                 // 806400
    const size_t off_cnt   = off_score + 806400;             // 32
    const size_t off_tot   = off_cnt + 32;                   // 32
    const size_t need_base = off_tot + 32;                   // 1,216,096
    const size_t off_cls   = need_base;                      // 806400
    const size_t need_full = off_cls + 806400;               // 2,022,496

    if (d_ws == nullptr || ws_size < need_base) {
        fallback_kernel<<<NB, 1024, 0, stream>>>(pred, logits, out);
        return;
    }

    char* ws = (char*)d_ws;
    ull*   mask_ws  = (ull*)(ws + off_mask);
    ull*   sel_key  = (ull*)(ws + off_key);
    float* sel_x1   = (float*)(ws + off_flt);
    float* sel_y1   = sel_x1 + NB * SELN;
    float* sel_x2   = sel_y1 + NB * SELN;
    float* sel_y2   = sel_x2 + NB * SELN;
    float* sel_area = sel_y2 + NB * SELN;
    float* sel_cls  = sel_area + NB * SELN;
    int*   sel_idx  = (int*)(ws + off_ix);
    float* score_ws = (float*)(ws + off_score);
    int*   cnt_ws   = (int*)(ws + off_cnt);
    int*   total_ws = (int*)(ws + off_tot);
    int*   cls_ws   = (int*)(ws + off_cls);
    int use_cls = (ws_size >= need_full) ? 1 : 0;

    prep_kernel<<<(NB * NN) / PREP_ROWS, 256, 0, stream>>>(pred, score_ws, cls_ws, use_cls);
    if (use_cls) {
        // 3-node path: fused select+attrs+mask at 4 blocks/image, 1024 threads
        selmask3_kernel<<<NB * 4, 1024, 0, stream>>>(pred, score_ws, cls_ws,
                                                     cnt_ws, total_ws, sel_key,
                                                     sel_x1, sel_y1, sel_x2, sel_y2,
                                                     sel_area, sel_cls, sel_idx, mask_ws);
    } else {
        selimg_kernel<<<NB, 1024, 0, stream>>>(pred, score_ws, cnt_ws, total_ws, sel_key,
                                               sel_x1, sel_y1, sel_x2, sel_y2,
                                               sel_area, sel_cls, sel_idx);
        mask_kernel<<<NB * 16, 256, 0, stream>>>(cnt_ws, sel_key,
                                                 sel_x1, sel_y1, sel_x2, sel_y2, sel_area, mask_ws);
    }
    resolve_kernel<<<NB, 1024, 0, stream>>>(pred, logits, score_ws, cls_ws, use_cls,
                                            cnt_ws, total_ws, mask_ws, sel_key,
                                            sel_x1, sel_y1, sel_x2, sel_y2,
                                            sel_area, sel_cls, sel_idx, out);
}

// Round 14
// 75.875 us; speedup vs baseline: 1.0469x; 1.0469x over previous
//
#include <hip/hip_runtime.h>

#pragma clang fp contract(off)

#define NB 8
#define NN 25200
#define NCLS 80
#define NSTR 85
#define MAXDET 300
#define CONF_T 0.4f
#define IOU_T 0.45f
#define MAX_WH_C 4096.0f

#define NBIN 1024
#define BINSHIFT 14
#define BINBASE 0x3EC00000u   // bits(0.375) < bits of any valid score (>0.4)
#define SELN 512
#define SORTN 2048            // tiny-ws fallback kernel only
#define PREP_ROWS 64

typedef unsigned long long ull;

// ---------------- helpers ----------------
__device__ __forceinline__ float cand_score(const float* __restrict__ p) {
    float obj = p[4];
    float best = p[5] * obj;
    for (int j = 1; j < NCLS; ++j) {
        float s = p[5 + j] * obj;
        if (s > best) best = s;
    }
    return ((obj > CONF_T) && (best > CONF_T)) ? best : -1.0f;
}
__device__ __forceinline__ int cand_cls(const float* __restrict__ p) {
    float obj = p[4];
    float best = p[5] * obj; int bc = 0;
    for (int j = 1; j < NCLS; ++j) {
        float s = p[5 + j] * obj;
        if (s > best) { best = s; bc = j; }   // strict >: first-index argmax
    }
    return bc;
}
__device__ __forceinline__ bool iou_gt(float ax1, float ay1, float ax2, float ay2, float aarea,
                                       float bx1, float by1, float bx2, float by2, float barea) {
    float lx = fmaxf(ax1, bx1);
    float ly = fmaxf(ay1, by1);
    float rx = fminf(ax2, bx2);
    float ry = fminf(ay2, by2);
    float iw = fmaxf(rx - lx, 0.0f);
    float ih = fmaxf(ry - ly, 0.0f);
    float inter = iw * ih;
    float iou = inter / ((aarea + barea - inter) + 1e-9f);
    return iou > IOU_T;
}

// =============== Kernel 1: score + class (float4 LDS staging; R4-validated cls path) ===============
__global__ __launch_bounds__(256) void prep_kernel(const float* __restrict__ pred,
                                                   float* __restrict__ score_ws,
                                                   int* __restrict__ cls_ws,
                                                   int write_cls) {
    __shared__ float st[PREP_ROWS * NSTR];   // 21760 B = 1360 float4
    const int R0 = blockIdx.x * PREP_ROWS;
    const float4* src = reinterpret_cast<const float4*>(pred + (size_t)R0 * NSTR);
    float4* dst4 = reinterpret_cast<float4*>(st);
    const int tid = threadIdx.x;
    for (int i = tid; i < PREP_ROWS * NSTR / 4; i += 256) dst4[i] = src[i];
    __syncthreads();

    int row = tid >> 2, part = tid & 3;
    const float* pr = st + row * NSTR;
    float obj = pr[4];
    float best = -1.0f; int bc = part * 20;
    const float* pc = pr + 5 + part * 20;
#pragma unroll
    for (int k = 0; k < 20; ++k) {
        float s = pc[k] * obj;
        if (s > best) { best = s; bc = part * 20 + k; }
    }
#pragma unroll
    for (int d = 1; d <= 2; d <<= 1) {
        float ob = __shfl_xor(best, d);
        int   oc = __shfl_xor(bc, d);
        if (ob > best || (ob == best && oc < bc)) { best = ob; bc = oc; }
    }
    if (part == 0) {
        int grow = R0 + row;
        bool valid = (obj > CONF_T) && (best > CONF_T);
        score_ws[grow] = valid ? best : -1.0f;
        if (write_cls) cls_ws[grow] = bc;
    }
}

// =============== Kernel 2: per-image hist + threshold + compact + attrs (8 blocks) ===============
__global__ __launch_bounds__(1024) void selimg_kernel(const float* __restrict__ pred,
                                                      const float* __restrict__ score_ws,
                                                      const int* __restrict__ cls_ws, int use_cls,
                                                      int* __restrict__ cnt_ws, int* __restrict__ total_ws,
                                                      ull* __restrict__ sel_key,
                                                      float* __restrict__ sel_x1, float* __restrict__ sel_y1,
                                                      float* __restrict__ sel_x2, float* __restrict__ sel_y2,
                                                      float* __restrict__ sel_area, float* __restrict__ sel_cls,
                                                      int* __restrict__ sel_idx) {
    __shared__ int s_hist[NBIN];
    __shared__ ull s_key[SELN];
    __shared__ int s_gidx[SELN];
    __shared__ int s_cnt, s_T, s_total;
    const int b = blockIdx.x;
    const int tid = threadIdx.x;
    const int lane = tid & 63;
    const int wid = tid >> 6;
    const float* predb = pred + (size_t)b * NN * NSTR;
    const float* sb = score_ws + (size_t)b * NN;

    s_hist[tid] = 0;
    if (tid == 0) s_cnt = 0;
    __syncthreads();
    for (int g = tid; g < NN; g += 1024) {
        float s = sb[g];
        if (s > 0.0f) {
            int bin = (int)((__float_as_uint(s) - BINBASE) >> BINSHIFT);
            atomicAdd(&s_hist[bin], 1);
        }
    }
    __syncthreads();
    if (wid == 0) {
        int acc = 0; int S[16];
#pragma unroll
        for (int k = 15; k >= 0; --k) { acc += s_hist[lane * 16 + k]; S[k] = acc; }
        int tot = acc;
        int incl = tot;
#pragma unroll
        for (int d = 1; d < 64; d <<= 1) {
            int v = __shfl_down(incl, d);
            if (lane + d < 64) incl += v;
        }
        int E = incl - tot;   // sum over lanes > lane
        int Tl = NBIN;
#pragma unroll
        for (int k = 0; k < 16; ++k)
            if (Tl == NBIN && S[k] + E <= SELN) Tl = lane * 16 + k;
        int total0 = incl;    // lane 0: grand total of valid
#pragma unroll
        for (int d = 1; d < 64; d <<= 1) {
            int o = __shfl_xor(Tl, d);
            if (o < Tl) Tl = o;
        }
        if (lane == 0) { s_T = Tl; s_total = total0; }
    }
    __syncthreads();
    int T = s_T;
    for (int g = tid; g < NN; g += 1024) {
        float s = sb[g];
        if (s > 0.0f) {
            int bin = (int)((__float_as_uint(s) - BINBASE) >> BINSHIFT);
            if (bin >= T) {
                int pos = atomicAdd(&s_cnt, 1);
                if (pos < SELN) {
                    s_key[pos] = ((ull)__float_as_uint(s) << 32)
                                 | (unsigned int)(0xFFFFFFFFu - (unsigned int)g);
                    s_gidx[pos] = g;
                }
            }
        }
    }
    __syncthreads();
    int cnt = s_cnt; if (cnt > SELN) cnt = SELN;

    // attrs: 4-float pred read + precomputed cls (85-float scan only if no cls_ws)
    if (tid < cnt) {
        int g = s_gidx[tid];
        const float* p = predb + (size_t)g * NSTR;
        float cx = p[0], cy = p[1], w = p[2], h = p[3];
        int c = use_cls ? cls_ws[(size_t)b * NN + g] : cand_cls(p);
        float off = (float)c * MAX_WH_C;
        float x1 = (cx - w * 0.5f) + off;
        float y1 = (cy - h * 0.5f) + off;
        float x2 = (cx + w * 0.5f) + off;
        float y2 = (cy + h * 0.5f) + off;
        int o = b * SELN + tid;
        sel_key[o] = s_key[tid];
        sel_x1[o] = x1; sel_y1[o] = y1; sel_x2[o] = x2; sel_y2[o] = y2;
        sel_area[o] = (x2 - x1) * (y2 - y1);
        sel_cls[o] = (float)c;
        sel_idx[o] = g;
    }
    if (tid == 0) { cnt_ws[b] = cnt; total_ws[b] = s_total; }
}

// =============== Kernel 3: mask in SLOT space, order predicate baked in (128 blocks) ===============
__global__ __launch_bounds__(256) void mask_kernel(const int* __restrict__ cnt_ws,
                                                   const ull* __restrict__ sel_key,
                                                   const float* __restrict__ sel_x1, const float* __restrict__ sel_y1,
                                                   const float* __restrict__ sel_x2, const float* __restrict__ sel_y2,
                                                   const float* __restrict__ sel_area,
                                                   ull* __restrict__ mask_ws) {
    __shared__ ull skey[SELN];
    __shared__ float ox1[SELN], oy1[SELN], ox2[SELN], oy2[SELN], oar[SELN];
    const int b = blockIdx.x >> 4;
    const int chunk = blockIdx.x & 15;
    const int tid = threadIdx.x;
    int cnt = cnt_ws[b]; if (cnt > SELN) cnt = SELN;
    for (int s = tid; s < SELN; s += 256) {
        if (s < cnt) {
            skey[s] = sel_key[b * SELN + s];
            ox1[s] = sel_x1[b * SELN + s]; oy1[s] = sel_y1[b * SELN + s];
            ox2[s] = sel_x2[b * SELN + s]; oy2[s] = sel_y2[b * SELN + s];
            oar[s] = sel_area[b * SELN + s];
        } else skey[s] = 0ull;
    }
    __syncthreads();
    int i = chunk * 32 + (tid & 31);
    int w = tid >> 5;
    if (i < cnt) {
        ull ki = skey[i];
        float ax1 = ox1[i], ay1 = oy1[i], ax2 = ox2[i], ay2 = oy2[i], aar = oar[i];
        ull m = 0ull;
        int jb = w << 6;
        int jend = cnt - jb; if (jend > 64) jend = 64;
        for (int t = 0; t < jend; ++t) {
            int j = jb + t;
            // j suppresses i iff j precedes i in score order AND IoU > thresh
            bool s = (skey[j] > ki) && iou_gt(ax1, ay1, ax2, ay2, aar,
                                             ox1[j], oy1[j], ox2[j], oy2[j], oar[j]);
            m |= (ull)s << t;
        }
        mask_ws[b * (8 * SELN) + w * SELN + i] = m;
    }
}

// =============== Kernel 4: Jacobi fixpoint (slot space) + ordered output ===============
__global__ __launch_bounds__(1024) void resolve_kernel(
        const float* __restrict__ pred, const float* __restrict__ logits,
        const float* __restrict__ score_ws, const int* __restrict__ cls_ws, int use_cls,
        const int* __restrict__ cnt_ws, const int* __restrict__ total_ws,
        const ull* __restrict__ mask_ws, const ull* __restrict__ sel_key,
        const float* __restrict__ sel_x1, const float* __restrict__ sel_y1,
        const float* __restrict__ sel_x2, const float* __restrict__ sel_y2,
        const float* __restrict__ sel_area, const float* __restrict__ sel_cls,
        const int* __restrict__ sel_idx,
        float* __restrict__ out) {
    __shared__ ull s_m[8][SELN];
    __shared__ ull s_key[SELN];
    __shared__ ull s_kw[8];
    __shared__ ull s_minkey;
    __shared__ float s_x1[SELN], s_y1[SELN], s_x2[SELN], s_y2[SELN], s_ar[SELN], s_cl[SELN];
    __shared__ int s_ix[SELN];
    __shared__ float kx1[MAXDET], ky1[MAXDET], kx2[MAXDET], ky2[MAXDET], kar[MAXDET];
    __shared__ float ksc[MAXDET], kcl[MAXDET];
    __shared__ int kix[MAXDET];
    __shared__ int s_kc;

    const int b = blockIdx.x;
    const int tid = threadIdx.x;
    const int lane = tid & 63;
    const int wid = tid >> 6;
    const float* predb = pred + (size_t)b * NN * NSTR;
    const float* logb  = logits + (size_t)b * NN * NCLS;
    const float* sb    = score_ws + (size_t)b * NN;

    int cnt = cnt_ws[b]; if (cnt > SELN) cnt = SELN;

    for (int i = tid; i < 8 * SELN; i += 1024)
        (&s_m[0][0])[i] = mask_ws[b * (8 * SELN) + i];
    for (int s = tid; s < SELN; s += 1024) {
        if (s < cnt) {
            s_key[s] = sel_key[b * SELN + s];
            s_x1[s] = sel_x1[b * SELN + s]; s_y1[s] = sel_y1[b * SELN + s];
            s_x2[s] = sel_x2[b * SELN + s]; s_y2[s] = sel_y2[b * SELN + s];
            s_ar[s] = sel_area[b * SELN + s]; s_cl[s] = sel_cls[b * SELN + s];
            s_ix[s] = sel_idx[b * SELN + s];
        } else s_key[s] = 0ull;
    }
    __syncthreads();

    if (wid == 0) {
        ull mk = ~0ull;
#pragma unroll
        for (int r = 0; r < 8; ++r) {
            int i = (r << 6) + lane;
            if (i < cnt) { ull k = s_key[i]; if (k < mk) mk = k; }
        }
#pragma unroll
        for (int d = 32; d >= 1; d >>= 1) {
            ull o = __shfl_xor(mk, d);
            if (o < mk) mk = o;
        }
        if (lane == 0) s_minkey = mk;

        ull vm[8], kw[8];
#pragma unroll
        for (int r = 0; r < 8; ++r) {
            int lo = r << 6;
            vm[r] = (cnt >= lo + 64) ? ~0ull : (cnt > lo ? ((1ull << (cnt - lo)) - 1ull) : 0ull);
            kw[r] = vm[r];
        }
        for (int round = 0; round < SELN; ++round) {
            ull nw[8];
#pragma unroll
            for (int r = 0; r < 8; ++r) {
                int i = (r << 6) + lane;
                ull supp = 0ull;
#pragma unroll
                for (int w = 0; w < 8; ++w) supp |= kw[w] & s_m[w][i];
                nw[r] = __ballot((int)(supp == 0ull)) & vm[r];
            }
            bool changed = false;
#pragma unroll
            for (int r = 0; r < 8; ++r) { changed |= (nw[r] != kw[r]); kw[r] = nw[r]; }
            if (!changed) break;
        }
        int totkept = 0;
#pragma unroll
        for (int r = 0; r < 8; ++r) totkept += __popcll(kw[r]);
        if (lane == 0) s_kc = totkept < MAXDET ? totkept : MAXDET;
        if (lane < 8) s_kw[lane] = kw[lane];
    }
    __syncthreads();
    int kc = s_kc;

    if (tid < SELN) {
        bool kept = (s_kw[tid >> 6] >> (tid & 63)) & 1ull;
        if (!kept) s_key[tid] = 0ull;
    }
    __syncthreads();

    {
        int i = tid >> 1, half = tid & 1;
        ull k = s_key[i];
        int r = 0;
        if (k != 0ull) {
            int jb = half << 8;
            for (int jj = 0; jj < 256; ++jj) {
                ull kj = s_key[jb + jj];
                r += (int)(kj > k);
            }
        }
        r += __shfl_xor(r, 1);
        if (half == 0 && k != 0ull && r < MAXDET) {
            kx1[r] = s_x1[i]; ky1[r] = s_y1[i]; kx2[r] = s_x2[i]; ky2[r] = s_y2[i];
            kar[r] = s_ar[i]; ksc[r] = __uint_as_float((unsigned int)(k >> 32));
            kcl[r] = s_cl[i]; kix[r] = s_ix[i];
        }
    }
    __syncthreads();

    if (wid == 0 && kc < MAXDET && total_ws[b] > cnt) {
        ull prevkey = (cnt > 0) ? s_minkey : ~0ull;
        while (kc < MAXDET) {
            ull best = 0ull;
            for (int i0 = lane; i0 < NN; i0 += 64) {
                float s = sb[i0];
                if (s > 0.0f) {
                    ull key = ((ull)__float_as_uint(s) << 32)
                              | (unsigned int)(0xFFFFFFFFu - (unsigned int)i0);
                    if (key < prevkey && key > best) best = key;
                }
            }
#pragma unroll
            for (int d = 32; d >= 1; d >>= 1) {
                ull o = __shfl_xor(best, d);
                if (o > best) best = o;
            }
            if (best == 0ull) break;
            prevkey = best;
            int gi = (int)(0xFFFFFFFFu - (unsigned int)(best & 0xFFFFFFFFull));
            float sc = __uint_as_float((unsigned int)(best >> 32));
            const float* pp = predb + (size_t)gi * NSTR;
            float cx = pp[0], cy = pp[1], w = pp[2], h = pp[3];
            int c = use_cls ? cls_ws[(size_t)b * NN + gi] : cand_cls(pp);
            float off = (float)c * MAX_WH_C;
            float x1 = (cx - w * 0.5f) + off;
            float y1 = (cy - h * 0.5f) + off;
            float x2 = (cx + w * 0.5f) + off;
            float y2 = (cy + h * 0.5f) + off;
            float ar = (x2 - x1) * (y2 - y1);
            bool f = false;
            for (int t = lane; t < kc; t += 64)
                if (iou_gt(kx1[t], ky1[t], kx2[t], ky2[t], kar[t], x1, y1, x2, y2, ar)) f = true;
            if (!__any((int)f)) {
                if (lane == 0) {
                    kx1[kc] = x1; ky1[kc] = y1; kx2[kc] = x2; ky2[kc] = y2;
                    kar[kc] = ar; ksc[kc] = sc; kcl[kc] = (float)c; kix[kc] = gi;
                }
                kc++;
            }
        }
        if (lane == 0) s_kc = kc;
    }
    __syncthreads();
    kc = s_kc;

    if (tid < MAXDET) {
        int t = tid;
        float o0 = 0, o1 = 0, o2 = 0, o3 = 0, o4 = 0, o5 = 0;
        if (t < kc) {
            int idx = kix[t];
            const float* pp = predb + (size_t)idx * NSTR;
            float cx = pp[0], cy = pp[1], w = pp[2], h = pp[3];
            o0 = cx - w * 0.5f; o1 = cy - h * 0.5f;
            o2 = cx + w * 0.5f; o3 = cy + h * 0.5f;
            o4 = ksc[t];        o5 = kcl[t];
        }
        float* dd = out + (size_t)b * (MAXDET * 6) + (size_t)t * 6;
        dd[0] = o0; dd[1] = o1; dd[2] = o2; dd[3] = o3; dd[4] = o4; dd[5] = o5;
        out[(size_t)NB * MAXDET * 6 + (size_t)NB * MAXDET * NCLS + (size_t)b * MAXDET + t] =
            (t < kc) ? 1.0f : 0.0f;
    }
    float* lbase = out + (size_t)NB * MAXDET * 6 + (size_t)b * (MAXDET * NCLS);
    for (int t = wid; t < MAXDET; t += 16) {
        float* dst = lbase + (size_t)t * NCLS;
        if (t < kc) {
            const float* src = logb + (size_t)kix[t] * NCLS;
            for (int c = lane; c < NCLS; c += 64) dst[c] = src[c];
        } else {
            for (int c = lane; c < NCLS; c += 64) dst[c] = 0.0f;
        }
    }
}

// ================= tiny-ws fallback (self-contained, round-2 proven) =================
__global__ __launch_bounds__(1024) void fallback_kernel(const float* __restrict__ pred,
                                                        const float* __restrict__ logits,
                                                        float* __restrict__ out) {
    __shared__ ull s_keys[SORTN];
    __shared__ float sel_x1[SORTN], sel_y1[SORTN], sel_x2[SORTN], sel_y2[SORTN];
    __shared__ float sel_area[SORTN], sel_cls[SORTN];
    __shared__ int   sel_idx[SORTN];
    __shared__ float kx1[MAXDET], ky1[MAXDET], kx2[MAXDET], ky2[MAXDET], karea[MAXDET];
    __shared__ float kscore[MAXDET], kcls[MAXDET];
    __shared__ int   kidx[MAXDET];
    __shared__ int   s_hist[NBIN];
    __shared__ int   s_suppk[64];
    __shared__ unsigned int s_supmask[64][2];
    __shared__ int   s_kc, s_T, s_cnt;

    const int b = blockIdx.x;
    const int tid = threadIdx.x;
    const int lane = tid & 63;
    const int wid = tid >> 6;
    const float* predb = pred + (size_t)b * NN * NSTR;
    const float* logb  = logits + (size_t)b * NN * NCLS;

    int kc_total = 0;
    int prevT = NBIN;

    while (kc_total < MAXDET && prevT > 0) {
        s_hist[tid] = 0;
        if (tid == 0) { s_cnt = 0; s_T = NBIN; }
        __syncthreads();
        for (int i = tid; i < NN; i += 1024) {
            float s = cand_score(predb + (size_t)i * NSTR);
            if (s > 0.0f) {
                int bin = (int)((__float_as_uint(s) - BINBASE) >> BINSHIFT);
                if (bin < prevT) atomicAdd(&s_hist[bin], 1);
            }
        }
        __syncthreads();
        for (int d = 1; d < NBIN; d <<= 1) {
            int v = s_hist[tid] + ((tid + d < NBIN) ? s_hist[tid + d] : 0);
            __syncthreads();
            s_hist[tid] = v;
            __syncthreads();
        }
        if (s_hist[tid] <= SORTN) atomicMin(&s_T, tid);
        __syncthreads();
        int T = s_T;
        int rem_total = s_hist[0];
        if (T >= prevT) {
            if (rem_total == 0) { prevT = 0; break; }
            T = prevT - 1;
        }
        __syncthreads();
        for (int i = tid; i < NN; i += 1024) {
            float s = cand_score(predb + (size_t)i * NSTR);
            if (s > 0.0f) {
                int bin = (int)((__float_as_uint(s) - BINBASE) >> BINSHIFT);
                if (bin >= T && bin < prevT) {
                    int pos = atomicAdd(&s_cnt, 1);
                    if (pos < SORTN)
                        s_keys[pos] = ((ull)__float_as_uint(s) << 32)
                                      | (unsigned int)(0xFFFFFFFFu - (unsigned int)i);
                }
            }
        }
        __syncthreads();
        int cnt = s_cnt; if (cnt > SORTN) cnt = SORTN;
        int npow = 64; while (npow < cnt) npow <<= 1;
        for (int i = cnt + tid; i < npow; i += 1024) s_keys[i] = 0ull;
        __syncthreads();
        for (int k = 2; k <= npow; k <<= 1) {
            for (int j = k >> 1; j > 0; j >>= 1) {
                for (int idx = tid; idx < npow; idx += 1024) {
                    int p = idx ^ j;
                    if (p > idx) {
                        ull a = s_keys[idx], c = s_keys[p];
                        bool desc = ((idx & k) == 0);
                        if (desc ? (a < c) : (a > c)) { s_keys[idx] = c; s_keys[p] = a; }
                    }
                }
                __syncthreads();
            }
        }
        for (int t = tid; t < cnt; t += 1024) {
            ull key = s_keys[t];
            int i = (int)(0xFFFFFFFFu - (unsigned int)(key & 0xFFFFFFFFull));
            const float* p = predb + (size_t)i * NSTR;
            float cx = p[0], cy = p[1], w = p[2], h = p[3];
            int c = cand_cls(p);
            float off = (float)c * MAX_WH_C;
            float x1 = (cx - w * 0.5f) + off;
            float y1 = (cy - h * 0.5f) + off;
            float x2 = (cx + w * 0.5f) + off;
            float y2 = (cy + h * 0.5f) + off;
            sel_x1[t] = x1; sel_y1[t] = y1; sel_x2[t] = x2; sel_y2[t] = y2;
            sel_area[t] = (x2 - x1) * (y2 - y1);
            sel_cls[t] = (float)c;
            sel_idx[t] = i;
        }
        __syncthreads();
        int nb2 = (cnt + 63) >> 6;
        for (int batch = 0; batch < nb2; ++batch) {
            int kcb = kc_total;
            if (kcb >= MAXDET) break;
            if (tid < 64) { s_suppk[tid] = 0; s_supmask[tid][0] = 0u; s_supmask[tid][1] = 0u; }
            __syncthreads();
            int cloc = tid >> 4, ch = tid & 15;
            int gi = batch * 64 + cloc;
            bool validc = gi < cnt;
            float ax1 = 0, ay1 = 0, ax2 = 0, ay2 = 0, aar = 0;
            if (validc) {
                ax1 = sel_x1[gi]; ay1 = sel_y1[gi];
                ax2 = sel_x2[gi]; ay2 = sel_y2[gi]; aar = sel_area[gi];
            }
            bool flag = false;
            if (validc) {
                for (int t = ch; t < kcb; t += 16) {
                    if (iou_gt(kx1[t], ky1[t], kx2[t], ky2[t], karea[t],
                               ax1, ay1, ax2, ay2, aar)) flag = true;
                }
            }
            ull bal = __ballot((int)flag);
            if ((lane & 15) == 0) {
                unsigned int sub = (unsigned int)((bal >> (lane & 48)) & 0xFFFFull);
                s_suppk[cloc] = (sub != 0u);
            }
            unsigned int mbits = 0;
            if (validc) {
                for (int jj = 0; jj < 4; ++jj) {
                    int j = (ch << 2) + jj;
                    int gj = batch * 64 + j;
                    if (j > cloc && gj < cnt) {
                        if (iou_gt(ax1, ay1, ax2, ay2, aar,
                                   sel_x1[gj], sel_y1[gj], sel_x2[gj], sel_y2[gj], sel_area[gj]))
                            mbits |= 1u << (j & 31);
                    }
                }
            }
            if (mbits) atomicOr(&s_supmask[cloc][(ch >> 3) & 1], mbits);
            __syncthreads();
            if (wid == 0) {
                ull mask = ((ull)s_supmask[lane][1] << 32) | s_supmask[lane][0];
                bool validj = (batch * 64 + lane) < cnt;
                ull rem = __ballot((int)(validj && (s_suppk[lane] == 0)));
                ull keepbits = 0;
                int kcount = kcb;
                while (rem && kcount < MAXDET) {
                    int i = __builtin_ctzll(rem);
                    rem &= rem - 1;
                    keepbits |= 1ull << i;
                    ++kcount;
                    ull mi = __shfl(mask, i);
                    rem &= ~mi;
                }
                if ((keepbits >> lane) & 1ull) {
                    int pos = kcb + __popcll(keepbits & ((1ull << lane) - 1ull));
                    int g2 = batch * 64 + lane;
                    kx1[pos] = sel_x1[g2]; ky1[pos] = sel_y1[g2];
                    kx2[pos] = sel_x2[g2]; ky2[pos] = sel_y2[g2];
                    karea[pos] = sel_area[g2];
                    kcls[pos] = sel_cls[g2]; kidx[pos] = sel_idx[g2];
                    kscore[pos] = __uint_as_float((unsigned int)(s_keys[g2] >> 32));
                }
                if (lane == 0) s_kc = kcount;
            }
            __syncthreads();
            kc_total = s_kc;
            __syncthreads();
        }
        prevT = T;
    }

    __syncthreads();
    int kc = kc_total;
    if (tid < MAXDET) {
        int t = tid;
        float o0 = 0, o1 = 0, o2 = 0, o3 = 0, o4 = 0, o5 = 0;
        if (t < kc) {
            int idx = kidx[t];
            const float* pp = predb + (size_t)idx * NSTR;
            float cx = pp[0], cy = pp[1], w = pp[2], h = pp[3];
            o0 = cx - w * 0.5f; o1 = cy - h * 0.5f;
            o2 = cx + w * 0.5f; o3 = cy + h * 0.5f;
            o4 = kscore[t];     o5 = kcls[t];
        }
        float* dd = out + (size_t)b * (MAXDET * 6) + (size_t)t * 6;
        dd[0] = o0; dd[1] = o1; dd[2] = o2; dd[3] = o3; dd[4] = o4; dd[5] = o5;
        out[(size_t)NB * MAXDET * 6 + (size_t)NB * MAXDET * NCLS + (size_t)b * MAXDET + t] =
            (t < kc) ? 1.0f : 0.0f;
    }
    float* lbase = out + (size_t)NB * MAXDET * 6 + (size_t)b * (MAXDET * NCLS);
    for (int t = wid; t < MAXDET; t += 16) {
        float* dst = lbase + (size_t)t * NCLS;
        if (t < kc) {
            const float* src = logb + (size_t)kidx[t] * NCLS;
            for (int c = lane; c < NCLS; c += 64) dst[c] = src[c];
        } else {
            for (int c = lane; c < NCLS; c += 64) dst[c] = 0.0f;
        }
    }
}

extern "C" void kernel_launch(void* const* d_in, const int* in_sizes, int n_in,
                              void* d_out, int out_size, void* d_ws, size_t ws_size,
                              hipStream_t stream) {
    const float* pred   = (const float*)d_in[0];
    const float* logits = (const float*)d_in[1];
    float* out = (float*)d_out;

    // ws layout (8B arrays first)
    const size_t off_mask  = 0;                              // 8*4096*8 = 262144
    const size_t off_key   = 262144;                         // 8*512*8 = 32768
    const size_t off_flt   = 294912;                         // 6 * 16384 = 98304
    const size_t off_ix    = off_flt + 6 * 16384;            // 16384
    const size_t off_score = off_ix + 16384;                 // 806400
    const size_t off_cnt   = off_score + 806400;             // 32
    const size_t off_tot   = off_cnt + 32;                   // 32
    const size_t need_base = off_tot + 32;                   // 1,216,096
    const size_t off_cls   = need_base;                      // 806400
    const size_t need_full = off_cls + 806400;               // 2,022,496

    if (d_ws == nullptr || ws_size < need_base) {
        fallback_kernel<<<NB, 1024, 0, stream>>>(pred, logits, out);
        return;
    }

    char* ws = (char*)d_ws;
    ull*   mask_ws  = (ull*)(ws + off_mask);
    ull*   sel_key  = (ull*)(ws + off_key);
    float* sel_x1   = (float*)(ws + off_flt);
    float* sel_y1   = sel_x1 + NB * SELN;
    float* sel_x2   = sel_y1 + NB * SELN;
    float* sel_y2   = sel_x2 + NB * SELN;
    float* sel_area = sel_y2 + NB * SELN;
    float* sel_cls  = sel_area + NB * SELN;
    int*   sel_idx  = (int*)(ws + off_ix);
    float* score_ws = (float*)(ws + off_score);
    int*   cnt_ws   = (int*)(ws + off_cnt);
    int*   total_ws = (int*)(ws + off_tot);
    int*   cls_ws   = (int*)(ws + off_cls);
    int use_cls = (ws_size >= need_full) ? 1 : 0;

    prep_kernel<<<(NB * NN) / PREP_ROWS, 256, 0, stream>>>(pred, score_ws, cls_ws, use_cls);
    selimg_kernel<<<NB, 1024, 0, stream>>>(pred, score_ws, cls_ws, use_cls,
                                           cnt_ws, total_ws, sel_key,
                                           sel_x1, sel_y1, sel_x2, sel_y2,
                                           sel_area, sel_cls, sel_idx);
    mask_kernel<<<NB * 16, 256, 0, stream>>>(cnt_ws, sel_key,
                                             sel_x1, sel_y1, sel_x2, sel_y2, sel_area, mask_ws);
    resolve_kernel<<<NB, 1024, 0, stream>>>(pred, logits, score_ws, cls_ws, use_cls,
                                            cnt_ws, total_ws, mask_ws, sel_key,
                                            sel_x1, sel_y1, sel_x2, sel_y2,
                                            sel_area, sel_cls, sel_idx, out);
}